// Round 10
// baseline (29.050 us; speedup 1.0000x reference)
//
#include <hip/hip_runtime.h>
#include <hip/hip_bf16.h>

#define IMG_H 512
#define IMG_W 512
#define NBLOCKS 256                      // 1 block per CU, perfectly balanced
#define TOTAL_ELEMS (48LL * 512 * 512)   // 16*3*512*512

__device__ __forceinline__ float fast_sqrtf(float x) {
    float r; asm("v_sqrt_f32 %0, %1" : "=v"(r) : "v"(x)); return r;   // ~1 ulp
}

__device__ __forceinline__ void load8(const float* __restrict__ p, float v[8]) {
    const float4 x = *reinterpret_cast<const float4*>(p);
    const float4 y = *reinterpret_cast<const float4*>(p + 4);
    v[0] = x.x; v[1] = x.y; v[2] = x.z; v[3] = x.w;
    v[4] = y.x; v[5] = y.y; v[6] = y.z; v[7] = y.w;
}

__device__ __forceinline__ void lds_read8(const float* __restrict__ s, float v[8]) {
    const float4 x = *reinterpret_cast<const float4*>(s);
    const float4 y = *reinterpret_cast<const float4*>(s + 4);
    v[0] = x.x; v[1] = x.y; v[2] = x.z; v[3] = x.w;
    v[4] = y.x; v[5] = y.y; v[6] = y.z; v[7] = y.w;
}

// Separable Sobel magnitude for one output row (8 px/lane); column halo via
// 2 shuffles on the linear vertical-pass terms (zero pad at image edges).
__device__ __forceinline__ void sobel_mag_row(const float t[8], const float m[8], const float b[8],
                                              int lane, float mag[8]) {
    float cs[8], rd[8];
#pragma unroll
    for (int j = 0; j < 8; ++j) {
        cs[j] = (t[j] + b[j]) + 2.0f * m[j];   // vertical [1,2,1]
        rd[j] = b[j] - t[j];                   // vertical [-1,0,1]
    }
    float csL = __shfl_up(cs[7], 1), csR = __shfl_down(cs[0], 1);
    float rdL = __shfl_up(rd[7], 1), rdR = __shfl_down(rd[0], 1);
    if (lane == 0)  { csL = 0.0f; rdL = 0.0f; }
    if (lane == 63) { csR = 0.0f; rdR = 0.0f; }
#pragma unroll
    for (int j = 0; j < 8; ++j) {
        const float ex = ((j == 7) ? csR : cs[j + 1]) - ((j == 0) ? csL : cs[j - 1]);
        const float ey = ((j == 0) ? rdL : rd[j - 1]) + 2.0f * rd[j] + ((j == 7) ? rdR : rd[j + 1]);
        mag[j] = fast_sqrtf(fmaf(ex, ex, fmaf(ey, ey, 1e-6f)));
    }
}

// R9 per-tile body verbatim; 256 blocks x 3 consecutive 32-row tiles each
// (48 planes * 16 tiles = 768 tiles). Tile k>0's top halo row comes from LDS
// (it is tile k-1's wave-7 boundary row, still resident) -> global halo loads
// drop to ~4 rows per 96 (amplification 1.042x). Perfect CU balance.
__global__ __launch_bounds__(512) void edge_loss_kernel(const float* __restrict__ img1,
                                                        const float* __restrict__ img2,
                                                        float* __restrict__ slots) {
    const int t = threadIdx.x;
    const int lane = t & 63;
    const int w = t >> 6;                           // 0..7
    const int bid = blockIdx.x;
    const int x0 = lane << 3;

    __shared__ float sh[2][8][2][IMG_W];            // 64 KB halo-exchange
    __shared__ float wave_sums[8];

    float sum = 0.0f;

#pragma unroll
    for (int k = 0; k < 3; ++k) {
        const int tile = bid * 3 + k;
        const int plane = tile >> 4;                // 16 tiles per plane
        const int blk = tile & 15;
        const int yb = blk << 5;                    // tile top row
        const int y0 = yb + (w << 2);               // this wave's first row
        const size_t base = (size_t)plane * (IMG_H * IMG_W);
        const float* p1 = img1 + base + x0;
        const float* p2 = img2 + base + x0;

        // leftover top halo: previous tile's wave-7 boundary row is still in LDS
        float ha[8], hb[8];
        bool fromLds = false;
        if (k > 0 && w == 0 && blk != 0) {          // wave-uniform
            lds_read8(&sh[0][7][1][x0], ha);
            lds_read8(&sh[1][7][1][x0], hb);
            fromLds = true;
        }
        __syncthreads();                            // leftover read before rewrite

        float a[4][8], b[4][8];
#pragma unroll
        for (int r = 0; r < 4; ++r) {
            load8(p1 + (size_t)(y0 + r) * IMG_W, a[r]);
            load8(p2 + (size_t)(y0 + r) * IMG_W, b[r]);
        }

        if (w == 0 && !fromLds) {
            if (blk == 0) {                         // plane top: zero pad
#pragma unroll
                for (int j = 0; j < 8; ++j) { ha[j] = 0.0f; hb[j] = 0.0f; }
            } else {                                // only k==0 lands here
                load8(p1 + (size_t)(yb - 1) * IMG_W, ha);
                load8(p2 + (size_t)(yb - 1) * IMG_W, hb);
            }
        } else if (w == 7) {
            if (blk == 15) {                        // plane bottom: zero pad
#pragma unroll
                for (int j = 0; j < 8; ++j) { ha[j] = 0.0f; hb[j] = 0.0f; }
            } else {
                load8(p1 + (size_t)(yb + 32) * IMG_W, ha);
                load8(p2 + (size_t)(yb + 32) * IMG_W, hb);
            }
        }

        *reinterpret_cast<float4*>(&sh[0][w][0][x0])     = make_float4(a[0][0], a[0][1], a[0][2], a[0][3]);
        *reinterpret_cast<float4*>(&sh[0][w][0][x0 + 4]) = make_float4(a[0][4], a[0][5], a[0][6], a[0][7]);
        *reinterpret_cast<float4*>(&sh[0][w][1][x0])     = make_float4(a[3][0], a[3][1], a[3][2], a[3][3]);
        *reinterpret_cast<float4*>(&sh[0][w][1][x0 + 4]) = make_float4(a[3][4], a[3][5], a[3][6], a[3][7]);
        *reinterpret_cast<float4*>(&sh[1][w][0][x0])     = make_float4(b[0][0], b[0][1], b[0][2], b[0][3]);
        *reinterpret_cast<float4*>(&sh[1][w][0][x0 + 4]) = make_float4(b[0][4], b[0][5], b[0][6], b[0][7]);
        *reinterpret_cast<float4*>(&sh[1][w][1][x0])     = make_float4(b[3][0], b[3][1], b[3][2], b[3][3]);
        *reinterpret_cast<float4*>(&sh[1][w][1][x0 + 4]) = make_float4(b[3][4], b[3][5], b[3][6], b[3][7]);
        __syncthreads();

        // assemble halo rows: top = row y0-1, bot = row y0+4 (per image)
        float ta[8], tb[8], ba[8], bb[8];
        if (w == 0) {
#pragma unroll
            for (int j = 0; j < 8; ++j) { ta[j] = ha[j]; tb[j] = hb[j]; }
        } else {
            lds_read8(&sh[0][w - 1][1][x0], ta);
            lds_read8(&sh[1][w - 1][1][x0], tb);
        }
        if (w == 7) {
#pragma unroll
            for (int j = 0; j < 8; ++j) { ba[j] = ha[j]; bb[j] = hb[j]; }
        } else {
            lds_read8(&sh[0][w + 1][0][x0], ba);
            lds_read8(&sh[1][w + 1][0][x0], bb);
        }

        // image 1 magnitudes, then image 2 + abs-diff accumulate
        float m1[4][8];
        sobel_mag_row(ta,   a[0], a[1], lane, m1[0]);
        sobel_mag_row(a[0], a[1], a[2], lane, m1[1]);
        sobel_mag_row(a[1], a[2], a[3], lane, m1[2]);
        sobel_mag_row(a[2], a[3], ba,   lane, m1[3]);

        {
            float m2[8];
            sobel_mag_row(tb,   b[0], b[1], lane, m2);
#pragma unroll
            for (int j = 0; j < 8; ++j) sum += fabsf(m1[0][j] - m2[j]);
            sobel_mag_row(b[0], b[1], b[2], lane, m2);
#pragma unroll
            for (int j = 0; j < 8; ++j) sum += fabsf(m1[1][j] - m2[j]);
            sobel_mag_row(b[1], b[2], b[3], lane, m2);
#pragma unroll
            for (int j = 0; j < 8; ++j) sum += fabsf(m1[2][j] - m2[j]);
            sobel_mag_row(b[2], b[3], bb,   lane, m2);
#pragma unroll
            for (int j = 0; j < 8; ++j) sum += fabsf(m1[3][j] - m2[j]);
        }
    }

#pragma unroll
    for (int off = 32; off > 0; off >>= 1) sum += __shfl_down(sum, off);

    if (lane == 0) wave_sums[w] = sum;
    __syncthreads();
    if (t == 0) {
        float s = 0.0f;
#pragma unroll
        for (int i = 0; i < 8; ++i) s += wave_sums[i];
        slots[bid] = s;
    }
}

// Deterministic fixed-order reduction of the 256 per-block partials.
__global__ __launch_bounds__(256) void finalize_kernel(const float* __restrict__ slots,
                                                       float* __restrict__ out) {
    const int t = threadIdx.x;
    const int lane = t & 63;
    const int w = t >> 6;
    float s = slots[t];
#pragma unroll
    for (int off = 32; off > 0; off >>= 1) s += __shfl_down(s, off);
    __shared__ float ws[4];
    if (lane == 0) ws[w] = s;
    __syncthreads();
    if (t == 0) out[0] = ((ws[0] + ws[1]) + (ws[2] + ws[3])) * (1.0f / (float)TOTAL_ELEMS);
}

extern "C" void kernel_launch(void* const* d_in, const int* in_sizes, int n_in,
                              void* d_out, int out_size, void* d_ws, size_t ws_size,
                              hipStream_t stream) {
    const float* img1 = (const float*)d_in[0];
    const float* img2 = (const float*)d_in[1];
    float* out = (float*)d_out;
    float* slots = (float*)d_ws;    // 256 floats, fully rewritten every call

    edge_loss_kernel<<<dim3(NBLOCKS), 512, 0, stream>>>(img1, img2, slots);
    finalize_kernel<<<dim3(1), 256, 0, stream>>>(slots, out);
}

// Round 11
// 27.342 us; speedup vs baseline: 1.0625x; 1.0625x over previous
//
#include <hip/hip_runtime.h>
#include <hip/hip_bf16.h>

#define IMG_H 512
#define IMG_W 512
#define NBLOCKS 1536
#define TOTAL_ELEMS (48LL * 512 * 512)   // 16*3*512*512

__device__ __forceinline__ float fast_sqrtf(float x) {
    float r; asm("v_sqrt_f32 %0, %1" : "=v"(r) : "v"(x)); return r;   // ~1 ulp
}

__device__ __forceinline__ void load8(const float* __restrict__ p, float v[8]) {
    const float4 x = *reinterpret_cast<const float4*>(p);
    const float4 y = *reinterpret_cast<const float4*>(p + 4);
    v[0] = x.x; v[1] = x.y; v[2] = x.z; v[3] = x.w;
    v[4] = y.x; v[5] = y.y; v[6] = y.z; v[7] = y.w;
}

__device__ __forceinline__ void lds_read8(const float* __restrict__ s, float v[8]) {
    const float4 x = *reinterpret_cast<const float4*>(s);
    const float4 y = *reinterpret_cast<const float4*>(s + 4);
    v[0] = x.x; v[1] = x.y; v[2] = x.z; v[3] = x.w;
    v[4] = y.x; v[5] = y.y; v[6] = y.z; v[7] = y.w;
}

__device__ __forceinline__ void lds_write8(float* s, const float v[8]) {
    *reinterpret_cast<float4*>(s)     = make_float4(v[0], v[1], v[2], v[3]);
    *reinterpret_cast<float4*>(s + 4) = make_float4(v[4], v[5], v[6], v[7]);
}

// Separable Sobel magnitude for one output row (8 px/lane); column halo via
// 2 shuffles on the linear vertical-pass terms (zero pad at image edges).
__device__ __forceinline__ void sobel_mag_row(const float t[8], const float m[8], const float b[8],
                                              int lane, float mag[8]) {
    float cs[8], rd[8];
#pragma unroll
    for (int j = 0; j < 8; ++j) {
        cs[j] = (t[j] + b[j]) + 2.0f * m[j];   // vertical [1,2,1]
        rd[j] = b[j] - t[j];                   // vertical [-1,0,1]
    }
    float csL = __shfl_up(cs[7], 1), csR = __shfl_down(cs[0], 1);
    float rdL = __shfl_up(rd[7], 1), rdR = __shfl_down(rd[0], 1);
    if (lane == 0)  { csL = 0.0f; rdL = 0.0f; }
    if (lane == 63) { csR = 0.0f; rdR = 0.0f; }
#pragma unroll
    for (int j = 0; j < 8; ++j) {
        const float ex = ((j == 7) ? csR : cs[j + 1]) - ((j == 0) ? csL : cs[j - 1]);
        const float ey = ((j == 0) ? rdL : rd[j - 1]) + 2.0f * rd[j] + ((j == 7) ? rdR : rd[j + 1]);
        mag[j] = fast_sqrtf(fmaf(ex, ex, fmaf(ey, ey, 1e-6f)));
    }
}

// R8 body with a minimal 6-row exchange buffer (w0's first / w3's last rows are
// never read -> don't publish them): LDS 32.5 -> 24.6 KB => 6 blocks/CU =
// 24 waves/CU (was 16). Slot map per image: L_w (last row of wave w) at [w],
// w=0..2; F_w (first row of wave w) at [w+2], w=1..3.
__global__ __launch_bounds__(256) void edge_loss_kernel(const float* __restrict__ img1,
                                                        const float* __restrict__ img2,
                                                        float* __restrict__ slots) {
    const int t = threadIdx.x;
    const int lane = t & 63;
    const int w = t >> 6;
    const int bid = blockIdx.x;
    const int swz = (bid & 7) * 192 + (bid >> 3);   // bijective XCD swizzle
    const int plane = swz >> 5;                     // 32 blocks per plane
    const int blk = swz & 31;
    const int yb = blk << 4;                        // tile top row
    const int y0 = yb + (w << 2);                   // this wave's first row
    const int x0 = lane << 3;
    const size_t base = (size_t)plane * (IMG_H * IMG_W);
    const float* p1 = img1 + base + x0;
    const float* p2 = img2 + base + x0;

    __shared__ float sh[2][6][IMG_W];               // 24.6 KB halo-exchange

    float a[4][8], b[4][8];
#pragma unroll
    for (int r = 0; r < 4; ++r) {
        load8(p1 + (size_t)(y0 + r) * IMG_W, a[r]);
        load8(p2 + (size_t)(y0 + r) * IMG_W, b[r]);
    }

    float ha[8], hb[8];
    bool hzero = false;
    if (w == 0) {
        hzero = (yb == 0);
        const int y = hzero ? 0 : yb - 1;
        load8(p1 + (size_t)y * IMG_W, ha);
        load8(p2 + (size_t)y * IMG_W, hb);
    } else if (w == 3) {
        hzero = (yb + 16 == IMG_H);
        const int y = hzero ? IMG_H - 1 : yb + 16;
        load8(p1 + (size_t)y * IMG_W, ha);
        load8(p2 + (size_t)y * IMG_W, hb);
    }
    if ((w == 0 || w == 3) && hzero) {
#pragma unroll
        for (int j = 0; j < 8; ++j) { ha[j] = 0.0f; hb[j] = 0.0f; }
    }

    // publish: last row (w<3) at slot [w], first row (w>0) at slot [w+2]
    if (w < 3) {
        lds_write8(&sh[0][w][x0], a[3]);
        lds_write8(&sh[1][w][x0], b[3]);
    }
    if (w > 0) {
        lds_write8(&sh[0][w + 2][x0], a[0]);
        lds_write8(&sh[1][w + 2][x0], b[0]);
    }
    __syncthreads();

    // assemble halo rows: top = row y0-1 (= L_{w-1}), bot = row y0+4 (= F_{w+1})
    float ta[8], tb[8], ba[8], bb[8];
    if (w == 0) {
#pragma unroll
        for (int j = 0; j < 8; ++j) { ta[j] = ha[j]; tb[j] = hb[j]; }
    } else {
        lds_read8(&sh[0][w - 1][x0], ta);
        lds_read8(&sh[1][w - 1][x0], tb);
    }
    if (w == 3) {
#pragma unroll
        for (int j = 0; j < 8; ++j) { ba[j] = ha[j]; bb[j] = hb[j]; }
    } else {
        lds_read8(&sh[0][w + 3][x0], ba);
        lds_read8(&sh[1][w + 3][x0], bb);
    }

    // image 1 magnitudes, then image 2 + abs-diff accumulate
    float m1[4][8];
    sobel_mag_row(ta,   a[0], a[1], lane, m1[0]);
    sobel_mag_row(a[0], a[1], a[2], lane, m1[1]);
    sobel_mag_row(a[1], a[2], a[3], lane, m1[2]);
    sobel_mag_row(a[2], a[3], ba,   lane, m1[3]);

    float sum = 0.0f;
    {
        float m2[8];
        sobel_mag_row(tb,   b[0], b[1], lane, m2);
#pragma unroll
        for (int j = 0; j < 8; ++j) sum += fabsf(m1[0][j] - m2[j]);
        sobel_mag_row(b[0], b[1], b[2], lane, m2);
#pragma unroll
        for (int j = 0; j < 8; ++j) sum += fabsf(m1[1][j] - m2[j]);
        sobel_mag_row(b[1], b[2], b[3], lane, m2);
#pragma unroll
        for (int j = 0; j < 8; ++j) sum += fabsf(m1[2][j] - m2[j]);
        sobel_mag_row(b[2], b[3], bb,   lane, m2);
#pragma unroll
        for (int j = 0; j < 8; ++j) sum += fabsf(m1[3][j] - m2[j]);
    }

#pragma unroll
    for (int off = 32; off > 0; off >>= 1) sum += __shfl_down(sum, off);

    __shared__ float wave_sums[4];
    if (lane == 0) wave_sums[w] = sum;
    __syncthreads();
    if (t == 0) {
        slots[bid] = (wave_sums[0] + wave_sums[1]) + (wave_sums[2] + wave_sums[3]);
    }
}

// Deterministic fixed-order reduction of the 1536 per-block partials.
__global__ __launch_bounds__(256) void finalize_kernel(const float* __restrict__ slots,
                                                       float* __restrict__ out) {
    const int t = threadIdx.x;
    const int lane = t & 63;
    const int w = t >> 6;
    float s = 0.0f;
#pragma unroll
    for (int i = 0; i < NBLOCKS / 256; ++i) s += slots[t + i * 256];
#pragma unroll
    for (int off = 32; off > 0; off >>= 1) s += __shfl_down(s, off);
    __shared__ float ws[4];
    if (lane == 0) ws[w] = s;
    __syncthreads();
    if (t == 0) out[0] = ((ws[0] + ws[1]) + (ws[2] + ws[3])) * (1.0f / (float)TOTAL_ELEMS);
}

extern "C" void kernel_launch(void* const* d_in, const int* in_sizes, int n_in,
                              void* d_out, int out_size, void* d_ws, size_t ws_size,
                              hipStream_t stream) {
    const float* img1 = (const float*)d_in[0];
    const float* img2 = (const float*)d_in[1];
    float* out = (float*)d_out;
    float* slots = (float*)d_ws;    // 1536 floats, fully rewritten every call

    edge_loss_kernel<<<dim3(NBLOCKS), 256, 0, stream>>>(img1, img2, slots);
    finalize_kernel<<<dim3(1), 256, 0, stream>>>(slots, out);
}